// Round 1
// baseline (61.533 us; speedup 1.0000x reference)
//
#include <hip/hip_runtime.h>

// Problem constants (match reference)
#define N_NODES  4096
#define MAX_PATH 5
#define EDGE_DIM 16

// One thread per pair: gather up to MAX_PATH edge_attr rows, dot with the
// per-hop edge_vector row, mean over valid hops, scatter to out[src*N + dst].
// Pair (src,dst) tuples are unique by construction -> plain stores, no atomics.
__global__ __launch_bounds__(256) void edge_encoding_kernel(
    const float* __restrict__ edge_attr,   // [N_EDGES, 16]
    const float* __restrict__ edge_vector, // [MAX_PATH, 16]
    const int*   __restrict__ src_idx,     // [P]
    const int*   __restrict__ dst_idx,     // [P]
    const int*   __restrict__ path_idx,    // [P, MAX_PATH]
    float*       __restrict__ out,         // [N_NODES, N_NODES]
    int n_pairs)
{
    int p = blockIdx.x * blockDim.x + threadIdx.x;
    if (p >= n_pairs) return;

    // Load the 5 path edge indices (20B/thread, contiguous across wave).
    int e[MAX_PATH];
#pragma unroll
    for (int l = 0; l < MAX_PATH; ++l)
        e[l] = path_idx[(size_t)p * MAX_PATH + l];

    float sum = 0.0f;
    int   cnt = 0;
#pragma unroll
    for (int l = 0; l < MAX_PATH; ++l) {
        if (e[l] >= 0) {
            const float4* ea = (const float4*)(edge_attr + (size_t)e[l] * EDGE_DIM);
            const float4* ev = (const float4*)(edge_vector + l * EDGE_DIM);
            float d = 0.0f;
#pragma unroll
            for (int q = 0; q < 4; ++q) {
                float4 a = ea[q];
                float4 b = ev[q];   // uniform across threads -> scalar-cached
                d += a.x * b.x + a.y * b.y + a.z * b.z + a.w * b.w;
            }
            sum += d;
            ++cnt;
        }
    }

    float val = (cnt > 0) ? (sum / (float)cnt) : 0.0f;
    out[(size_t)src_idx[p] * N_NODES + dst_idx[p]] = val;
}

extern "C" void kernel_launch(void* const* d_in, const int* in_sizes, int n_in,
                              void* d_out, int out_size, void* d_ws, size_t ws_size,
                              hipStream_t stream)
{
    // Input order per setup_inputs(): x, edge_attr, edge_vector, src_idx, dst_idx, path_idx
    const float* edge_attr   = (const float*)d_in[1];
    const float* edge_vector = (const float*)d_in[2];
    const int*   src_idx     = (const int*)d_in[3];
    const int*   dst_idx     = (const int*)d_in[4];
    const int*   path_idx    = (const int*)d_in[5];
    float*       out         = (float*)d_out;

    const int n_pairs = in_sizes[3];  // 1,000,000

    // Zero the dense output (scatter only touches ~1M of 16.7M entries).
    hipMemsetAsync(d_out, 0, (size_t)out_size * sizeof(float), stream);

    const int block = 256;
    const int grid  = (n_pairs + block - 1) / block;
    edge_encoding_kernel<<<grid, block, 0, stream>>>(
        edge_attr, edge_vector, src_idx, dst_idx, path_idx, out, n_pairs);
}

// Round 2
// 47.873 us; speedup vs baseline: 1.2853x; 1.2853x over previous
//
#include <hip/hip_runtime.h>

// Problem constants (match reference)
#define N_NODES  4096
#define MAX_PATH 5
#define EDGE_DIM 16

// Phase 1: precompute D[l][e] = dot(edge_attr[e], edge_vector[l]).
// 100K threads, each reads one 64B edge_attr row and writes 5 floats
// (coalesced per hop-plane). Output table = 5*100K*4B = 2MB -> fits the
// 4MiB per-XCD L2, turning the main kernel's gathers into L2 hits.
__global__ __launch_bounds__(256) void precompute_dots_kernel(
    const float* __restrict__ edge_attr,   // [E, 16]
    const float* __restrict__ edge_vector, // [MAX_PATH, 16]
    float*       __restrict__ D,           // [MAX_PATH, E]
    int n_edges)
{
    int e = blockIdx.x * blockDim.x + threadIdx.x;
    if (e >= n_edges) return;

    const float4* ea = (const float4*)(edge_attr + (size_t)e * EDGE_DIM);
    float4 a0 = ea[0], a1 = ea[1], a2 = ea[2], a3 = ea[3];

#pragma unroll
    for (int l = 0; l < MAX_PATH; ++l) {
        const float4* ev = (const float4*)(edge_vector + l * EDGE_DIM);
        float4 b0 = ev[0], b1 = ev[1], b2 = ev[2], b3 = ev[3];
        float d = a0.x*b0.x + a0.y*b0.y + a0.z*b0.z + a0.w*b0.w
                + a1.x*b1.x + a1.y*b1.y + a1.z*b1.z + a1.w*b1.w
                + a2.x*b2.x + a2.y*b2.y + a2.z*b2.z + a2.w*b2.w
                + a3.x*b3.x + a3.y*b3.y + a3.z*b3.z + a3.w*b3.w;
        D[(size_t)l * n_edges + e] = d;
    }
}

// Phase 2: per pair, gather up to 5 precomputed dots (4B each, L2-resident),
// mean over valid hops, scatter to out[src*N + dst]. Pairs unique -> plain store.
__global__ __launch_bounds__(256) void edge_encoding_kernel(
    const float* __restrict__ D,        // [MAX_PATH, E]
    const int*   __restrict__ src_idx,  // [P]
    const int*   __restrict__ dst_idx,  // [P]
    const int*   __restrict__ path_idx, // [P, MAX_PATH]
    float*       __restrict__ out,      // [N_NODES, N_NODES]
    int n_pairs, int n_edges)
{
    int p = blockIdx.x * blockDim.x + threadIdx.x;
    if (p >= n_pairs) return;

    int e[MAX_PATH];
#pragma unroll
    for (int l = 0; l < MAX_PATH; ++l)
        e[l] = path_idx[(size_t)p * MAX_PATH + l];

    float sum = 0.0f;
    int   cnt = 0;
#pragma unroll
    for (int l = 0; l < MAX_PATH; ++l) {
        if (e[l] >= 0) {
            sum += D[(size_t)l * n_edges + e[l]];   // independent 4B gathers, L2-hit
            ++cnt;
        }
    }

    float val = (cnt > 0) ? (sum / (float)cnt) : 0.0f;
    out[(size_t)src_idx[p] * N_NODES + dst_idx[p]] = val;
}

extern "C" void kernel_launch(void* const* d_in, const int* in_sizes, int n_in,
                              void* d_out, int out_size, void* d_ws, size_t ws_size,
                              hipStream_t stream)
{
    // Input order: x, edge_attr, edge_vector, src_idx, dst_idx, path_idx
    const float* edge_attr   = (const float*)d_in[1];
    const float* edge_vector = (const float*)d_in[2];
    const int*   src_idx     = (const int*)d_in[3];
    const int*   dst_idx     = (const int*)d_in[4];
    const int*   path_idx    = (const int*)d_in[5];
    float*       out         = (float*)d_out;
    float*       D           = (float*)d_ws;   // 5 * n_edges * 4B = 2 MB

    const int n_edges = in_sizes[1] / EDGE_DIM;  // 100,000
    const int n_pairs = in_sizes[3];             // 1,000,000

    // Zero the dense output (scatter only touches ~1M of 16.7M entries).
    hipMemsetAsync(d_out, 0, (size_t)out_size * sizeof(float), stream);

    const int block = 256;
    precompute_dots_kernel<<<(n_edges + block - 1) / block, block, 0, stream>>>(
        edge_attr, edge_vector, D, n_edges);

    edge_encoding_kernel<<<(n_pairs + block - 1) / block, block, 0, stream>>>(
        D, src_idx, dst_idx, path_idx, out, n_pairs, n_edges);
}

// Round 3
// 47.172 us; speedup vs baseline: 1.3044x; 1.0149x over previous
//
#include <hip/hip_runtime.h>

// Problem constants (match reference)
#define N_NODES  4096
#define MAX_PATH 5
#define EDGE_DIM 16

// Phase 1: precompute D[l][e] = dot(edge_attr[e], edge_vector[l]).
// 2 MB table -> L2-resident in every XCD for the gather phase.
__global__ __launch_bounds__(256) void precompute_dots_kernel(
    const float* __restrict__ edge_attr,   // [E, 16]
    const float* __restrict__ edge_vector, // [MAX_PATH, 16]
    float*       __restrict__ D,           // [MAX_PATH, E]
    int n_edges)
{
    int e = blockIdx.x * blockDim.x + threadIdx.x;
    if (e >= n_edges) return;

    const float4* ea = (const float4*)(edge_attr + (size_t)e * EDGE_DIM);
    float4 a0 = ea[0], a1 = ea[1], a2 = ea[2], a3 = ea[3];

#pragma unroll
    for (int l = 0; l < MAX_PATH; ++l) {
        const float4* ev = (const float4*)(edge_vector + l * EDGE_DIM);
        float4 b0 = ev[0], b1 = ev[1], b2 = ev[2], b3 = ev[3];
        float d = a0.x*b0.x + a0.y*b0.y + a0.z*b0.z + a0.w*b0.w
                + a1.x*b1.x + a1.y*b1.y + a1.z*b1.z + a1.w*b1.w
                + a2.x*b2.x + a2.y*b2.y + a2.z*b2.z + a2.w*b2.w
                + a3.x*b3.x + a3.y*b3.y + a3.z*b3.z + a3.w*b3.w;
        D[(size_t)l * n_edges + e] = d;
    }
}

// Phase 2: 4 pairs per thread. Vectorized int4 index loads (no redundant
// cache-line touches), 20 independent L2 gathers in flight per thread,
// 4 scatter stores. Fully unrolled constant-bound loops (no scratch).
__global__ __launch_bounds__(256) void edge_encoding_kernel(
    const float* __restrict__ D,        // [MAX_PATH, E]
    const int*   __restrict__ src_idx,  // [P]
    const int*   __restrict__ dst_idx,  // [P]
    const int*   __restrict__ path_idx, // [P, MAX_PATH]
    float*       __restrict__ out,      // [N_NODES, N_NODES]
    int n_pairs, int n_edges)
{
    int t  = blockIdx.x * blockDim.x + threadIdx.x;
    int p0 = t * 4;
    if (p0 >= n_pairs) return;

    if (p0 + 3 < n_pairs) {
        // 20 path ints for 4 pairs = 5 aligned int4 loads (80B, 16B-aligned).
        const int4* pp = (const int4*)(path_idx + (size_t)p0 * MAX_PATH);
        int4 w0 = pp[0], w1 = pp[1], w2 = pp[2], w3 = pp[3], w4 = pp[4];
        int e[20] = { w0.x, w0.y, w0.z, w0.w,
                      w1.x, w1.y, w1.z, w1.w,
                      w2.x, w2.y, w2.z, w2.w,
                      w3.x, w3.y, w3.z, w3.w,
                      w4.x, w4.y, w4.z, w4.w };

        // Issue all gathers (independent -> deep MLP), compile-time indices only.
        float g[20];
#pragma unroll
        for (int j = 0; j < 4; ++j) {
#pragma unroll
            for (int l = 0; l < MAX_PATH; ++l) {
                int idx = e[j * MAX_PATH + l];
                g[j * MAX_PATH + l] = (idx >= 0) ? D[(size_t)l * n_edges + idx] : 0.0f;
            }
        }

        int4 sv = *(const int4*)(src_idx + p0);   // p0 % 4 == 0 -> 16B aligned
        int4 dv = *(const int4*)(dst_idx + p0);
        int srcs[4] = { sv.x, sv.y, sv.z, sv.w };
        int dsts[4] = { dv.x, dv.y, dv.z, dv.w };

#pragma unroll
        for (int j = 0; j < 4; ++j) {
            float sum = 0.0f;
            int   cnt = 0;
#pragma unroll
            for (int l = 0; l < MAX_PATH; ++l) {
                int idx = e[j * MAX_PATH + l];
                if (idx >= 0) { sum += g[j * MAX_PATH + l]; ++cnt; }
            }
            float val = (cnt > 0) ? (sum / (float)cnt) : 0.0f;
            out[(size_t)srcs[j] * N_NODES + dsts[j]] = val;
        }
    } else {
        // Tail: scalar path (never taken for n_pairs % 4 == 0).
        for (int p = p0; p < n_pairs; ++p) {
            float sum = 0.0f;
            int   cnt = 0;
#pragma unroll
            for (int l = 0; l < MAX_PATH; ++l) {
                int idx = path_idx[(size_t)p * MAX_PATH + l];
                if (idx >= 0) { sum += D[(size_t)l * n_edges + idx]; ++cnt; }
            }
            float val = (cnt > 0) ? (sum / (float)cnt) : 0.0f;
            out[(size_t)src_idx[p] * N_NODES + dst_idx[p]] = val;
        }
    }
}

extern "C" void kernel_launch(void* const* d_in, const int* in_sizes, int n_in,
                              void* d_out, int out_size, void* d_ws, size_t ws_size,
                              hipStream_t stream)
{
    // Input order: x, edge_attr, edge_vector, src_idx, dst_idx, path_idx
    const float* edge_attr   = (const float*)d_in[1];
    const float* edge_vector = (const float*)d_in[2];
    const int*   src_idx     = (const int*)d_in[3];
    const int*   dst_idx     = (const int*)d_in[4];
    const int*   path_idx    = (const int*)d_in[5];
    float*       out         = (float*)d_out;
    float*       D           = (float*)d_ws;   // 5 * n_edges * 4B = 2 MB

    const int n_edges = in_sizes[1] / EDGE_DIM;  // 100,000
    const int n_pairs = in_sizes[3];             // 1,000,000

    hipMemsetAsync(d_out, 0, (size_t)out_size * sizeof(float), stream);

    const int block = 256;
    precompute_dots_kernel<<<(n_edges + block - 1) / block, block, 0, stream>>>(
        edge_attr, edge_vector, D, n_edges);

    const int threads_needed = (n_pairs + 3) / 4;
    edge_encoding_kernel<<<(threads_needed + block - 1) / block, block, 0, stream>>>(
        D, src_idx, dst_idx, path_idx, out, n_pairs, n_edges);
}